// Round 1
// baseline (795.332 us; speedup 1.0000x reference)
//
#include <hip/hip_runtime.h>
#include <math.h>

#define NB 32       // batch
#define NS 2048     // seq
#define NE 1024     // embed
#define NR 512      // reasoning dim
#define FR 2048     // 4*NR
#define NSTEPS 8

// workspace layout (float offsets)
#define SCAL   ((size_t)0)                       // 1024 floats of scalars (memset to 0 each call)
//   [0] enc |W| sum  [1] dec |W| sum  [2] gate |W| sum
//   [4] mean absmax (uint bits, atomicMax)  [5] final absmax (float)
//   [8..15] per-step h absmax (uint bits, atomicMax)
#define PART   ((size_t)1024)                    // 32*32*1024 partial seq sums
#define WT_IH  (PART + (size_t)NB*32*NE)         // 512*2048  W_ih^T
#define WT_SUM (WT_IH + (size_t)NR*FR)           // 512*2048  (W_ih+W_hh)^T
#define MEANB  (WT_SUM + (size_t)NR*FR)          // 32*1024
#define HBUF   (MEANB + (size_t)NB*NE)           // 9*32*512 (hbuf[0]=enc out, hbuf[1+t]=h_t)
#define CBUF   (HBUF + (size_t)9*NB*NR)          // 32*512
#define FINALB (CBUF + (size_t)NB*NR)            // 32*512
#define ROUTB  (FINALB + (size_t)NB*NR)          // 32*1024

__device__ __forceinline__ float sigf(float x){ return 1.0f/(1.0f+expf(-x)); }
__device__ __forceinline__ float quant8(float x, float isc){
    return fminf(fmaxf(rintf(x/isc), -128.0f), 127.0f);
}
__device__ __forceinline__ float tern(float w, float thr){
    return (fabsf(w) > thr) ? (w > 0.0f ? 1.0f : -1.0f) : 0.0f;
}

// ---------------- K_pre: x partial sums + weight transposes + |W| sums ----------------
__global__ __launch_bounds__(256) void k_pre(
    const float4* __restrict__ x4, const float* __restrict__ Wih,
    const float* __restrict__ Whh, const float* __restrict__ encW,
    const float* __restrict__ decW, const float* __restrict__ gateW,
    float* __restrict__ ws)
{
    const int blk = blockIdx.x, tid = threadIdx.x;
    if (blk < 1024) {
        // partial sums over seq: block = (b, chunk of 64 rows)
        const int b = blk >> 5, ch = blk & 31;
        const float4* xp = x4 + ((size_t)(b*NS + ch*64))*(NE/4) + tid;
        float4 a; a.x=0.f; a.y=0.f; a.z=0.f; a.w=0.f;
        #pragma unroll 4
        for (int i = 0; i < 64; i++) {
            float4 v = xp[(size_t)i*(NE/4)];
            a.x += v.x; a.y += v.y; a.z += v.z; a.w += v.w;
        }
        float4* pp = (float4*)(ws + PART) + (size_t)blk*(NE/4) + tid;
        *pp = a;
    } else if (blk < 1280) {
        // transpose W_ih and W_ih+W_hh in 64x64 tiles
        const int tt = blk - 1024, jt = tt & 31, kt = tt >> 5;
        const int j0 = jt*64, k0 = kt*64;
        __shared__ float t_ih[64][65];
        __shared__ float t_sm[64][65];
        const int kk = tid & 63, j4 = tid >> 6;
        for (int p = 0; p < 16; p++) {
            int jj = p*4 + j4;
            float a = Wih[(size_t)(j0+jj)*NR + k0 + kk];
            float c = Whh[(size_t)(j0+jj)*NR + k0 + kk];
            t_ih[jj][kk] = a; t_sm[jj][kk] = a + c;
        }
        __syncthreads();
        const int jjj = tid & 63, k4 = tid >> 6;
        for (int p = 0; p < 16; p++) {
            int k2 = p*4 + k4;
            ws[WT_IH  + (size_t)(k0+k2)*FR + j0 + jjj] = t_ih[jjj][k2];
            ws[WT_SUM + (size_t)(k0+k2)*FR + j0 + jjj] = t_sm[jjj][k2];
        }
    } else {
        // abs-sum reductions
        const float4* w4; int n4; int lb; float* dst;
        if (blk < 1344)      { w4=(const float4*)encW;  n4=NR*NE/4; lb=blk-1280; dst=ws+SCAL+0; }
        else if (blk < 1408) { w4=(const float4*)decW;  n4=NE*NR/4; lb=blk-1344; dst=ws+SCAL+1; }
        else                 { w4=(const float4*)gateW; n4=NR/4;    lb=0;        dst=ws+SCAL+2; }
        float a = 0.f;
        for (int i = lb*256 + tid; i < n4; i += 64*256) {
            float4 v = w4[i];
            a += fabsf(v.x)+fabsf(v.y)+fabsf(v.z)+fabsf(v.w);
        }
        for (int o = 32; o > 0; o >>= 1) a += __shfl_down(a, o, 64);
        __shared__ float lds[4];
        if ((tid & 63) == 0) lds[tid >> 6] = a;
        __syncthreads();
        if (tid == 0) atomicAdd(dst, lds[0]+lds[1]+lds[2]+lds[3]);
    }
}

// ---------------- K_mean: finalize mean + global absmax ----------------
__global__ __launch_bounds__(256) void k_mean(float* __restrict__ ws)
{
    const int b = blockIdx.x, tid = threadIdx.x;
    const float4* pp = (const float4*)(ws + PART) + (size_t)b*32*(NE/4);
    float4 a; a.x=0.f; a.y=0.f; a.z=0.f; a.w=0.f;
    #pragma unroll 4
    for (int c = 0; c < 32; c++) {
        float4 v = pp[(size_t)c*(NE/4) + tid];
        a.x += v.x; a.y += v.y; a.z += v.z; a.w += v.w;
    }
    const float inv = 1.0f/(float)NS;
    a.x *= inv; a.y *= inv; a.z *= inv; a.w *= inv;
    ((float4*)(ws + MEANB))[(size_t)b*(NE/4) + tid] = a;
    float m = fmaxf(fmaxf(fabsf(a.x), fabsf(a.y)), fmaxf(fabsf(a.z), fabsf(a.w)));
    for (int o = 32; o > 0; o >>= 1) m = fmaxf(m, __shfl_down(m, o, 64));
    __shared__ float lds[4];
    if ((tid & 63) == 0) lds[tid >> 6] = m;
    __syncthreads();
    if (tid == 0) {
        m = fmaxf(fmaxf(lds[0], lds[1]), fmaxf(lds[2], lds[3]));
        atomicMax((unsigned int*)(ws + SCAL + 4), __float_as_uint(m));
    }
}

// ---------------- K_enc: bit_linear(mean, enc_W) -> hbuf[0]; zero c ----------------
__global__ __launch_bounds__(256) void k_enc(
    const float* __restrict__ encW, const float* __restrict__ encB,
    float* __restrict__ ws)
{
    const int blk = blockIdx.x, tid = threadIdx.x;
    const int b = blk >> 1;
    const int r = ((blk & 1) << 8) + tid;
    const float wsc = ws[SCAL+0] * (1.0f/(float)(NR*NE));
    const float thr = 0.5f*wsc;
    const float amax = __uint_as_float(((const unsigned int*)(ws + SCAL))[4]);
    const float isc = amax / 127.0f;
    __shared__ float qx[NE];
    const float* mrow = ws + MEANB + (size_t)b*NE;
    for (int e = tid; e < NE; e += 256) qx[e] = quant8(mrow[e], isc);
    __syncthreads();
    const float4* w4 = (const float4*)(encW + (size_t)r*NE);
    float acc = 0.f;
    #pragma unroll 4
    for (int e = 0; e < NE; e += 4) {
        float4 w = w4[e >> 2];
        acc += qx[e  ]*tern(w.x, thr) + qx[e+1]*tern(w.y, thr)
             + qx[e+2]*tern(w.z, thr) + qx[e+3]*tern(w.w, thr);
    }
    ws[HBUF + (size_t)b*NR + r] = acc*wsc*isc + encB[r];
    ws[CBUF + (size_t)b*NR + r] = 0.f;
}

// ---------------- K_step: one LSTM step (fused matmul + cell) ----------------
// grid 64 blocks x 1024 threads. tid = kq*256 + b*8 + rl; block r-tile = 8.
__global__ __launch_bounds__(1024) void k_step(
    const float* __restrict__ wt, const float* __restrict__ bih,
    const float* __restrict__ bhh, float* __restrict__ ws, int t)
{
    const int tid = threadIdx.x, blk = blockIdx.x;
    const int kq = tid >> 8, bi = (tid >> 3) & 31, rl = tid & 7;
    const int r0 = blk*8;
    const float* hprev = ws + HBUF + (size_t)t*NB*NR;
    const float* hrow = hprev + (size_t)bi*NR + kq*128;
    const float* wk = wt + (size_t)(kq*128)*FR + r0 + rl;
    float a0=0.f, a1=0.f, a2=0.f, a3=0.f;
    for (int kk = 0; kk < 128; kk += 4) {
        float4 h4 = *(const float4*)(hrow + kk);
        const float* w0 = wk + (size_t)kk*FR;
        a0 += h4.x*w0[0];        a1 += h4.x*w0[NR];        a2 += h4.x*w0[2*NR];        a3 += h4.x*w0[3*NR];
        a0 += h4.y*w0[FR];       a1 += h4.y*w0[FR+NR];     a2 += h4.y*w0[FR+2*NR];     a3 += h4.y*w0[FR+3*NR];
        a0 += h4.z*w0[2*FR];     a1 += h4.z*w0[2*FR+NR];   a2 += h4.z*w0[2*FR+2*NR];   a3 += h4.z*w0[2*FR+3*NR];
        a0 += h4.w*w0[3*FR];     a1 += h4.w*w0[3*FR+NR];   a2 += h4.w*w0[3*FR+2*NR];   a3 += h4.w*w0[3*FR+3*NR];
    }
    __shared__ float part[4][256][4];
    const int bp = bi*8 + rl;
    part[kq][bp][0]=a0; part[kq][bp][1]=a1; part[kq][bp][2]=a2; part[kq][bp][3]=a3;
    __syncthreads();
    __shared__ float redmax[4];
    float hn = 0.f;
    if (tid < 256) {
        const int bb = tid >> 3, rr = tid & 7;
        const int r = r0 + rr;
        float gi = part[0][tid][0]+part[1][tid][0]+part[2][tid][0]+part[3][tid][0] + (bih[r]        + bhh[r]);
        float gf = part[0][tid][1]+part[1][tid][1]+part[2][tid][1]+part[3][tid][1] + (bih[NR+r]     + bhh[NR+r]);
        float gg = part[0][tid][2]+part[1][tid][2]+part[2][tid][2]+part[3][tid][2] + (bih[2*NR+r]   + bhh[2*NR+r]);
        float go = part[0][tid][3]+part[1][tid][3]+part[2][tid][3]+part[3][tid][3] + (bih[3*NR+r]   + bhh[3*NR+r]);
        float c  = ws[CBUF + (size_t)bb*NR + r];
        float cn = sigf(gf)*c + sigf(gi)*tanhf(gg);
        hn = sigf(go)*tanhf(cn);
        ws[CBUF + (size_t)bb*NR + r] = cn;
        ws[HBUF + (size_t)(t+1)*NB*NR + (size_t)bb*NR + r] = hn;
    }
    float m = fabsf(hn);
    for (int o = 32; o > 0; o >>= 1) m = fmaxf(m, __shfl_down(m, o, 64));
    if (tid < 256 && (tid & 63) == 0) redmax[tid >> 6] = m;
    __syncthreads();
    if (tid == 0) {
        m = fmaxf(fmaxf(redmax[0], redmax[1]), fmaxf(redmax[2], redmax[3]));
        atomicMax((unsigned int*)(ws + SCAL + 8 + t), __float_as_uint(m));
    }
}

// ---------------- K_gate: per-step gate scores, weights, masked-mean final ----------------
__global__ __launch_bounds__(256) void k_gate(
    const float* __restrict__ gateW, const float* __restrict__ gateB,
    float* __restrict__ ws)
{
    const int tid = threadIdx.x;
    __shared__ float qgw[NR];
    __shared__ float lp[256];
    __shared__ float logits[NB];
    __shared__ float red[4];
    const float gwsc = ws[SCAL+2] * (1.0f/(float)NR);
    const float gthr = 0.5f*gwsc;
    for (int i = tid; i < NR; i += 256) qgw[i] = tern(gateW[i], gthr);
    const float gb = gateB[0];
    __syncthreads();
    bool active = true;
    float wts[NSTEPS];
    for (int t = 0; t < NSTEPS; t++) {
        const float amax = __uint_as_float(((const unsigned int*)(ws + SCAL))[8+t]);
        const float isc = amax / 127.0f;
        const float* h = ws + HBUF + (size_t)(t+1)*NB*NR;
        const int b = tid >> 3, ch = tid & 7;
        const float* hb = h + (size_t)b*NR + ch*64;
        float s = 0.f;
        for (int i = 0; i < 64; i++) s += quant8(hb[i], isc) * qgw[ch*64 + i];
        lp[tid] = s;
        __syncthreads();
        if (tid < NB) {
            float z = 0.f;
            for (int c = 0; c < 8; c++) z += lp[tid*8 + c];
            logits[tid] = z*gwsc*isc + gb;
        }
        __syncthreads();
        bool allneg = true;
        for (int bb = 0; bb < NB; bb++)
            allneg = allneg && (sigf(logits[bb]) < 0.5f);
        const bool trigger = allneg && (t > 2);
        wts[t] = active ? 1.0f : 0.0f;
        active = active && !trigger;
        __syncthreads();
    }
    float wsum = 0.f;
    for (int t = 0; t < NSTEPS; t++) wsum += wts[t];
    float m = 0.f;
    for (int i = tid; i < NB*NR; i += 256) {
        float f = 0.f;
        for (int t = 0; t < NSTEPS; t++) f += wts[t]*ws[HBUF + (size_t)(t+1)*NB*NR + i];
        f /= wsum;
        ws[FINALB + i] = f;
        m = fmaxf(m, fabsf(f));
    }
    for (int o = 32; o > 0; o >>= 1) m = fmaxf(m, __shfl_down(m, o, 64));
    if ((tid & 63) == 0) red[tid >> 6] = m;
    __syncthreads();
    if (tid == 0) ws[SCAL+5] = fmaxf(fmaxf(red[0], red[1]), fmaxf(red[2], red[3]));
}

// ---------------- K_dec: bit_linear(final, dec_W) -> r_out ----------------
__global__ __launch_bounds__(256) void k_dec(
    const float* __restrict__ decW, const float* __restrict__ decB,
    float* __restrict__ ws)
{
    const int blk = blockIdx.x, tid = threadIdx.x;
    const int b = blk >> 2;
    const int e = ((blk & 3) << 8) + tid;
    const float wsc = ws[SCAL+1] * (1.0f/(float)(NE*NR));
    const float thr = 0.5f*wsc;
    const float isc = ws[SCAL+5] / 127.0f;
    __shared__ float qf[NR];
    const float* frow = ws + FINALB + (size_t)b*NR;
    for (int i = tid; i < NR; i += 256) qf[i] = quant8(frow[i], isc);
    __syncthreads();
    const float4* w4 = (const float4*)(decW + (size_t)e*NR);
    float acc = 0.f;
    #pragma unroll 4
    for (int r = 0; r < NR; r += 4) {
        float4 w = w4[r >> 2];
        acc += qf[r  ]*tern(w.x, thr) + qf[r+1]*tern(w.y, thr)
             + qf[r+2]*tern(w.z, thr) + qf[r+3]*tern(w.w, thr);
    }
    ws[ROUTB + (size_t)b*NE + e] = acc*wsc*isc + decB[e];
}

// ---------------- K_out: out = x + r_out broadcast over seq ----------------
__global__ __launch_bounds__(256) void k_out(
    const float4* __restrict__ x4, const float* __restrict__ ws,
    float4* __restrict__ out4)
{
    const float4* r4 = (const float4*)(ws + ROUTB);
    const size_t base = (size_t)blockIdx.x*1024 + threadIdx.x;
    #pragma unroll
    for (int i = 0; i < 4; i++) {
        size_t f = base + (size_t)i*256;
        int e4 = (int)(f & 255);
        int b  = (int)(f >> 19);            // S*E/4 = 2^19 per batch
        float4 xv = x4[f];
        float4 rv = r4[(size_t)b*256 + e4];
        float4 o; o.x = xv.x+rv.x; o.y = xv.y+rv.y; o.z = xv.z+rv.z; o.w = xv.w+rv.w;
        out4[f] = o;
    }
}

extern "C" void kernel_launch(void* const* d_in, const int* in_sizes, int n_in,
                              void* d_out, int out_size, void* d_ws, size_t ws_size,
                              hipStream_t stream)
{
    const float* x     = (const float*)d_in[0];
    const float* encW  = (const float*)d_in[1];
    const float* encB  = (const float*)d_in[2];
    const float* Wih   = (const float*)d_in[3];
    const float* Whh   = (const float*)d_in[4];
    const float* bih   = (const float*)d_in[5];
    const float* bhh   = (const float*)d_in[6];
    const float* decW  = (const float*)d_in[7];
    const float* decB  = (const float*)d_in[8];
    const float* gateW = (const float*)d_in[9];
    const float* gateB = (const float*)d_in[10];
    float* ws  = (float*)d_ws;
    float* out = (float*)d_out;

    hipMemsetAsync(d_ws, 0, 4096, stream);   // zero scalar block (atomic accumulators)

    hipLaunchKernelGGL(k_pre, dim3(1409), dim3(256), 0, stream,
                       (const float4*)x, Wih, Whh, encW, decW, gateW, ws);
    hipLaunchKernelGGL(k_mean, dim3(32), dim3(256), 0, stream, ws);
    hipLaunchKernelGGL(k_enc, dim3(64), dim3(256), 0, stream, encW, encB, ws);
    for (int t = 0; t < NSTEPS; t++) {
        const float* wt = ws + (t == 0 ? WT_IH : WT_SUM);
        hipLaunchKernelGGL(k_step, dim3(64), dim3(1024), 0, stream, wt, bih, bhh, ws, t);
    }
    hipLaunchKernelGGL(k_gate, dim3(1), dim3(256), 0, stream, gateW, gateB, ws);
    hipLaunchKernelGGL(k_dec, dim3(128), dim3(256), 0, stream, decW, decB, ws);
    hipLaunchKernelGGL(k_out, dim3(16384), dim3(256), 0, stream,
                       (const float4*)x, ws, (float4*)out);
}

// Round 2
// 641.528 us; speedup vs baseline: 1.2397x; 1.2397x over previous
//
#include <hip/hip_runtime.h>
#include <math.h>

#define NB 32       // batch
#define NS 2048     // seq
#define NE 1024     // embed
#define NR 512      // reasoning dim
#define FR 2048     // 4*NR
#define NSTEPS 8

// workspace layout (float offsets)
#define SCAL   ((size_t)0)                       // scalars (memset to 0 each call)
//   [0] enc|W|sum [1] dec|W|sum [2] gate|W|sum
//   [4] mean absmax (uint bits) [5] final absmax (uint bits)
//   [8..15] per-step h absmax (uint bits)
//   [64..319] gate logits [8 steps][32 batch]
#define PART   ((size_t)1024)                     // 32*32*1024 partial seq sums
#define WB_IH  (PART + (size_t)NB*32*NE)          // 2048*512 bf16 W_ih (orig layout)
#define WB_SUM (WB_IH + (size_t)FR*NR/2)          // 2048*512 bf16 W_ih+W_hh
#define MEANB  (WB_SUM + (size_t)FR*NR/2)         // 32*1024 fp32
#define HBUF   (MEANB + (size_t)NB*NE)            // 9*32*512 fp32 (h0=enc out)
#define HBUFB  (HBUF + (size_t)9*NB*NR)           // 9*32*512 bf16
#define CBUF   (HBUFB + (size_t)9*NB*NR/2)        // 32*512 fp32
#define FINALB (CBUF + (size_t)NB*NR)             // 32*512 fp32
#define ROUTB  (FINALB + (size_t)NB*NR)           // 32*1024 fp32
#define LOGIT  (SCAL + 64)

typedef __attribute__((ext_vector_type(8))) short bf16x8;
typedef __attribute__((ext_vector_type(4))) float f32x4;

__device__ __forceinline__ float sigf(float x){ return 1.0f/(1.0f+expf(-x)); }
__device__ __forceinline__ float quant8(float x, float isc){
    return fminf(fmaxf(rintf(x/isc), -128.0f), 127.0f);
}
__device__ __forceinline__ float tern(float w, float thr){
    return (fabsf(w) > thr) ? (w > 0.0f ? 1.0f : -1.0f) : 0.0f;
}
__device__ __forceinline__ unsigned short f2b(float x){   // fp32 -> bf16 RNE
    unsigned u = __float_as_uint(x);
    return (unsigned short)((u + 0x7fffu + ((u >> 16) & 1u)) >> 16);
}

// ---------------- K_pre: x partial sums + bf16 weight converts + |W| sums ----------------
__global__ __launch_bounds__(256) void k_pre(
    const float4* __restrict__ x4, const float* __restrict__ Wih,
    const float* __restrict__ Whh, const float* __restrict__ encW,
    const float* __restrict__ decW, const float* __restrict__ gateW,
    float* __restrict__ ws)
{
    const int blk = blockIdx.x, tid = threadIdx.x;
    if (blk < 1024) {
        // partial sums over seq: block = (b, chunk of 64 rows)
        const int b = blk >> 5, ch = blk & 31;
        const float4* xp = x4 + ((size_t)(b*NS + ch*64))*(NE/4) + tid;
        float4 a; a.x=0.f; a.y=0.f; a.z=0.f; a.w=0.f;
        #pragma unroll 4
        for (int i = 0; i < 64; i++) {
            float4 v = xp[(size_t)i*(NE/4)];
            a.x += v.x; a.y += v.y; a.z += v.z; a.w += v.w;
        }
        float4* pp = (float4*)(ws + PART) + (size_t)blk*(NE/4) + tid;
        *pp = a;
    } else if (blk < 1152) {
        // bf16 convert: W_ih and (W_ih+W_hh), original [2048][512] layout
        const int lb = blk - 1024;
        const float4* wih4 = (const float4*)Wih;
        const float4* whh4 = (const float4*)Whh;
        ushort4* bi = (ushort4*)(ws + WB_IH);
        ushort4* bs = (ushort4*)(ws + WB_SUM);
        #pragma unroll
        for (int i = 0; i < 8; i++) {
            const int idx = lb*256 + tid + i*32768;   // 128*256=32768; 8 iters -> 262144 float4s
            float4 a = wih4[idx];
            float4 c = whh4[idx];
            ushort4 va; va.x=f2b(a.x); va.y=f2b(a.y); va.z=f2b(a.z); va.w=f2b(a.w);
            ushort4 vs; vs.x=f2b(a.x+c.x); vs.y=f2b(a.y+c.y); vs.z=f2b(a.z+c.z); vs.w=f2b(a.w+c.w);
            bi[idx] = va; bs[idx] = vs;
        }
    } else {
        // abs-sum reductions
        const float4* w4; int n4; int lb; float* dst;
        if (blk < 1216)      { w4=(const float4*)encW;  n4=NR*NE/4; lb=blk-1152; dst=ws+SCAL+0; }
        else if (blk < 1280) { w4=(const float4*)decW;  n4=NE*NR/4; lb=blk-1216; dst=ws+SCAL+1; }
        else                 { w4=(const float4*)gateW; n4=NR/4;    lb=0;        dst=ws+SCAL+2; }
        float a = 0.f;
        for (int i = lb*256 + tid; i < n4; i += 64*256) {
            float4 v = w4[i];
            a += fabsf(v.x)+fabsf(v.y)+fabsf(v.z)+fabsf(v.w);
        }
        for (int o = 32; o > 0; o >>= 1) a += __shfl_down(a, o, 64);
        __shared__ float lds[4];
        if ((tid & 63) == 0) lds[tid >> 6] = a;
        __syncthreads();
        if (tid == 0) atomicAdd(dst, lds[0]+lds[1]+lds[2]+lds[3]);
    }
}

// ---------------- K_mean: finalize mean + global absmax ----------------
__global__ __launch_bounds__(256) void k_mean(float* __restrict__ ws)
{
    const int b = blockIdx.x, tid = threadIdx.x;
    const float4* pp = (const float4*)(ws + PART) + (size_t)b*32*(NE/4);
    float4 a; a.x=0.f; a.y=0.f; a.z=0.f; a.w=0.f;
    #pragma unroll 4
    for (int c = 0; c < 32; c++) {
        float4 v = pp[(size_t)c*(NE/4) + tid];
        a.x += v.x; a.y += v.y; a.z += v.z; a.w += v.w;
    }
    const float inv = 1.0f/(float)NS;
    a.x *= inv; a.y *= inv; a.z *= inv; a.w *= inv;
    ((float4*)(ws + MEANB))[(size_t)b*(NE/4) + tid] = a;
    float m = fmaxf(fmaxf(fabsf(a.x), fabsf(a.y)), fmaxf(fabsf(a.z), fabsf(a.w)));
    for (int o = 32; o > 0; o >>= 1) m = fmaxf(m, __shfl_down(m, o, 64));
    __shared__ float lds[4];
    if ((tid & 63) == 0) lds[tid >> 6] = m;
    __syncthreads();
    if (tid == 0) {
        m = fmaxf(fmaxf(lds[0], lds[1]), fmaxf(lds[2], lds[3]));
        atomicMax((unsigned int*)(ws + SCAL + 4), __float_as_uint(m));
    }
}

// ---------------- K_enc: bit_linear(mean, enc_W) -> h0 (fp32 + bf16); zero c ----------------
__global__ __launch_bounds__(256) void k_enc(
    const float* __restrict__ encW, const float* __restrict__ encB,
    float* __restrict__ ws)
{
    const int blk = blockIdx.x, tid = threadIdx.x;
    const int b = blk >> 1;
    const int r = ((blk & 1) << 8) + tid;
    const float wsc = ws[SCAL+0] * (1.0f/(float)(NR*NE));
    const float thr = 0.5f*wsc;
    const float amax = __uint_as_float(((const unsigned int*)(ws + SCAL))[4]);
    const float isc = amax / 127.0f;
    __shared__ float qx[NE];
    const float* mrow = ws + MEANB + (size_t)b*NE;
    for (int e = tid; e < NE; e += 256) qx[e] = quant8(mrow[e], isc);
    __syncthreads();
    const float4* w4 = (const float4*)(encW + (size_t)r*NE);
    float acc = 0.f;
    #pragma unroll 4
    for (int e = 0; e < NE; e += 4) {
        float4 w = w4[e >> 2];
        acc += qx[e  ]*tern(w.x, thr) + qx[e+1]*tern(w.y, thr)
             + qx[e+2]*tern(w.z, thr) + qx[e+3]*tern(w.w, thr);
    }
    const float h0 = acc*wsc*isc + encB[r];
    ws[HBUF + (size_t)b*NR + r] = h0;
    ((unsigned short*)(ws + HBUFB))[(size_t)b*NR + r] = f2b(h0);
    ws[CBUF + (size_t)b*NR + r] = 0.f;
}

// ---------------- K_step: one LSTM step via bf16 MFMA, fused cell update ----------------
// grid 64 blocks x 256 thr. blk = (r_tile<<1)|m_tile. wave w computes gate w for
// 16 r-values x 16 batches; cell update fused after LDS exchange.
__global__ __launch_bounds__(256) void k_step(
    const unsigned short* __restrict__ wb,   // [2048][512] bf16 (original layout)
    const float* __restrict__ bih, const float* __restrict__ bhh,
    float* __restrict__ ws, int t)
{
    const int tid = threadIdx.x;
    const int wv = tid >> 6, lane = tid & 63;
    const int n = lane & 15, quad = lane >> 4;
    const int mt = blockIdx.x & 1;
    const int r0 = (blockIdx.x >> 1) << 4;
    const unsigned short* hb = (const unsigned short*)(ws + HBUFB) + (size_t)t*NB*NR;
    // A-frag: lane holds A[m=lane&15][k=quad*8+j] (m -> batch mt*16+n)
    const unsigned short* ap = hb + (size_t)(mt*16 + n)*NR + quad*8;
    // B-frag: lane holds B[k=quad*8+j][n=lane&15]; B[k][n]=W[j_out=n][k] -> orig row-major W
    const unsigned short* bp = wb + (size_t)((wv << 9) + r0 + n)*NR + quad*8;
    f32x4 acc = {0.f, 0.f, 0.f, 0.f};
    #pragma unroll
    for (int k0 = 0; k0 < NR; k0 += 32) {
        bf16x8 af = *(const bf16x8*)(ap + k0);
        bf16x8 bf_ = *(const bf16x8*)(bp + k0);
        acc = __builtin_amdgcn_mfma_f32_16x16x32_bf16(af, bf_, acc, 0, 0, 0);
    }
    // C/D layout: col=lane&15 (r), row=quad*4+reg (batch-local)
    __shared__ float g[4][16][17];
    #pragma unroll
    for (int reg = 0; reg < 4; reg++)
        g[wv][quad*4 + reg][n] = acc[reg];
    __syncthreads();
    // cell update: one (b,r) per thread
    const int bl = tid >> 4, rl = tid & 15;
    const int r = r0 + rl, b = mt*16 + bl;
    const float gi = g[0][bl][rl] + bih[r]        + bhh[r];
    const float gf = g[1][bl][rl] + bih[NR+r]     + bhh[NR+r];
    const float gg = g[2][bl][rl] + bih[2*NR+r]   + bhh[2*NR+r];
    const float go = g[3][bl][rl] + bih[3*NR+r]   + bhh[3*NR+r];
    const float c  = ws[CBUF + (size_t)b*NR + r];
    const float cn = sigf(gf)*c + sigf(gi)*tanhf(gg);
    const float hn = sigf(go)*tanhf(cn);
    ws[CBUF + (size_t)b*NR + r] = cn;
    ws[HBUF + (size_t)(t+1)*NB*NR + (size_t)b*NR + r] = hn;
    ((unsigned short*)(ws + HBUFB))[(size_t)(t+1)*NB*NR + (size_t)b*NR + r] = f2b(hn);
    float m = fabsf(hn);
    for (int o = 32; o > 0; o >>= 1) m = fmaxf(m, __shfl_down(m, o, 64));
    __shared__ float red[4];
    if (lane == 0) red[wv] = m;
    __syncthreads();
    if (tid == 0) {
        m = fmaxf(fmaxf(red[0], red[1]), fmaxf(red[2], red[3]));
        atomicMax((unsigned int*)(ws + SCAL + 8 + t), __float_as_uint(m));
    }
}

// ---------------- K_glog: gate logits, one block per step ----------------
__global__ __launch_bounds__(256) void k_glog(
    const float* __restrict__ gateW, const float* __restrict__ gateB,
    float* __restrict__ ws)
{
    const int t = blockIdx.x, tid = threadIdx.x;
    __shared__ float qgw[NR];
    __shared__ float lp[256];
    const float gwsc = ws[SCAL+2] * (1.0f/(float)NR);
    const float gthr = 0.5f*gwsc;
    for (int i = tid; i < NR; i += 256) qgw[i] = tern(gateW[i], gthr);
    __syncthreads();
    const float amax = __uint_as_float(((const unsigned int*)(ws + SCAL))[8 + t]);
    const float isc = amax / 127.0f;
    const float* h = ws + HBUF + (size_t)(t+1)*NB*NR;
    const int b = tid >> 3, ch = tid & 7;
    const float* hbp = h + (size_t)b*NR + ch*64;
    float s = 0.f;
    for (int i = 0; i < 64; i++) s += quant8(hbp[i], isc) * qgw[ch*64 + i];
    lp[tid] = s;
    __syncthreads();
    if (tid < NB) {
        float z = 0.f;
        for (int c = 0; c < 8; c++) z += lp[tid*8 + c];
        ws[LOGIT + t*32 + tid] = z*gwsc*isc + gateB[0];
    }
}

// ---------------- K_final: step weights + masked mean + absmax ----------------
__global__ __launch_bounds__(256) void k_final(float* __restrict__ ws)
{
    const int tid = threadIdx.x, blk = blockIdx.x;
    float wts[NSTEPS];
    bool active = true;
    #pragma unroll
    for (int t = 0; t < NSTEPS; t++) {
        bool allneg = true;
        for (int b = 0; b < NB; b++)
            allneg = allneg && (ws[LOGIT + t*32 + b] < 0.0f);   // sigmoid(z)<0.5 <=> z<0
        const bool trig = allneg && (t > 2);
        wts[t] = active ? 1.0f : 0.0f;
        active = active && !trig;
    }
    float wsum = 0.f;
    #pragma unroll
    for (int t = 0; t < NSTEPS; t++) wsum += wts[t];
    const float inv = 1.0f/wsum;
    float m = 0.f;
    const int i0 = blk*512 + tid;
    #pragma unroll
    for (int rep = 0; rep < 2; rep++) {
        const int i = i0 + rep*256;
        float f = 0.f;
        #pragma unroll
        for (int t = 0; t < NSTEPS; t++)
            f += wts[t]*ws[HBUF + (size_t)(t+1)*NB*NR + i];
        f *= inv;
        ws[FINALB + i] = f;
        m = fmaxf(m, fabsf(f));
    }
    for (int o = 32; o > 0; o >>= 1) m = fmaxf(m, __shfl_down(m, o, 64));
    __shared__ float red[4];
    if ((tid & 63) == 0) red[tid >> 6] = m;
    __syncthreads();
    if (tid == 0) {
        m = fmaxf(fmaxf(red[0], red[1]), fmaxf(red[2], red[3]));
        atomicMax((unsigned int*)(ws + SCAL + 5), __float_as_uint(m));
    }
}

// ---------------- K_dec: bit_linear(final, dec_W) -> r_out ----------------
__global__ __launch_bounds__(256) void k_dec(
    const float* __restrict__ decW, const float* __restrict__ decB,
    float* __restrict__ ws)
{
    const int blk = blockIdx.x, tid = threadIdx.x;
    const int b = blk >> 2;
    const int e = ((blk & 3) << 8) + tid;
    const float wsc = ws[SCAL+1] * (1.0f/(float)(NE*NR));
    const float thr = 0.5f*wsc;
    const float isc = __uint_as_float(((const unsigned int*)(ws + SCAL))[5]) / 127.0f;
    __shared__ float qf[NR];
    const float* frow = ws + FINALB + (size_t)b*NR;
    for (int i = tid; i < NR; i += 256) qf[i] = quant8(frow[i], isc);
    __syncthreads();
    const float4* w4 = (const float4*)(decW + (size_t)e*NR);
    float acc = 0.f;
    #pragma unroll 4
    for (int r = 0; r < NR; r += 4) {
        float4 w = w4[r >> 2];
        acc += qf[r  ]*tern(w.x, thr) + qf[r+1]*tern(w.y, thr)
             + qf[r+2]*tern(w.z, thr) + qf[r+3]*tern(w.w, thr);
    }
    ws[ROUTB + (size_t)b*NE + e] = acc*wsc*isc + decB[e];
}

// ---------------- K_out: out = x + r_out broadcast over seq ----------------
__global__ __launch_bounds__(256) void k_out(
    const float4* __restrict__ x4, const float* __restrict__ ws,
    float4* __restrict__ out4)
{
    const float4* r4 = (const float4*)(ws + ROUTB);
    const size_t base = (size_t)blockIdx.x*1024 + threadIdx.x;
    #pragma unroll
    for (int i = 0; i < 4; i++) {
        size_t f = base + (size_t)i*256;
        int e4 = (int)(f & 255);
        int b  = (int)(f >> 19);            // S*E/4 = 2^19 per batch
        float4 xv = x4[f];
        float4 rv = r4[(size_t)b*256 + e4];
        float4 o; o.x = xv.x+rv.x; o.y = xv.y+rv.y; o.z = xv.z+rv.z; o.w = xv.w+rv.w;
        out4[f] = o;
    }
}

extern "C" void kernel_launch(void* const* d_in, const int* in_sizes, int n_in,
                              void* d_out, int out_size, void* d_ws, size_t ws_size,
                              hipStream_t stream)
{
    const float* x     = (const float*)d_in[0];
    const float* encW  = (const float*)d_in[1];
    const float* encB  = (const float*)d_in[2];
    const float* Wih   = (const float*)d_in[3];
    const float* Whh   = (const float*)d_in[4];
    const float* bih   = (const float*)d_in[5];
    const float* bhh   = (const float*)d_in[6];
    const float* decW  = (const float*)d_in[7];
    const float* decB  = (const float*)d_in[8];
    const float* gateW = (const float*)d_in[9];
    const float* gateB = (const float*)d_in[10];
    float* ws  = (float*)d_ws;
    float* out = (float*)d_out;

    hipMemsetAsync(d_ws, 0, 4096, stream);   // zero scalar block (atomic accumulators)

    hipLaunchKernelGGL(k_pre, dim3(1281), dim3(256), 0, stream,
                       (const float4*)x, Wih, Whh, encW, decW, gateW, ws);
    hipLaunchKernelGGL(k_mean, dim3(32), dim3(256), 0, stream, ws);
    hipLaunchKernelGGL(k_enc, dim3(64), dim3(256), 0, stream, encW, encB, ws);
    for (int t = 0; t < NSTEPS; t++) {
        const unsigned short* wb =
            (const unsigned short*)(ws + (t == 0 ? WB_IH : WB_SUM));
        hipLaunchKernelGGL(k_step, dim3(64), dim3(256), 0, stream, wb, bih, bhh, ws, t);
    }
    hipLaunchKernelGGL(k_glog, dim3(8), dim3(256), 0, stream, gateW, gateB, ws);
    hipLaunchKernelGGL(k_final, dim3(32), dim3(256), 0, stream, ws);
    hipLaunchKernelGGL(k_dec, dim3(128), dim3(256), 0, stream, decW, decB, ws);
    hipLaunchKernelGGL(k_out, dim3(16384), dim3(256), 0, stream,
                       (const float4*)x, ws, (float4*)out);
}